// Round 1
// baseline (3422.144 us; speedup 1.0000x reference)
//
#include <hip/hip_runtime.h>

#define HEADS 16
#define DIM_HEAD 64
#define T_SEQ 16
#define D_MODEL 1024
#define MAX_REL 16

// ---------------------------------------------------------------------------
// GEMM: C[M,N] = A[M,K] * B[N,K]^T (+bias optional). Row-major, K contiguous
// for both operands (matches x @ W^T with W stored [N,K]).
// 128x128 tile, BK=16, 256 threads, 8x8 per-thread micro-tile, fp32.
// ---------------------------------------------------------------------------
constexpr int BM = 128, BN = 128, BK = 16;

__global__ __launch_bounds__(256)
void gemm_xwt(const float* __restrict__ A, const float* __restrict__ B,
              const float* __restrict__ bias, float* __restrict__ C,
              int M, int N, int K) {
  __shared__ float As[BK][BM];
  __shared__ float Bs[BK][BN];
  const int tid = threadIdx.x;
  const int bm = blockIdx.y, bn = blockIdx.x;
  const int ty = tid >> 4, tx = tid & 15;

  float acc[8][8];
#pragma unroll
  for (int i = 0; i < 8; ++i)
#pragma unroll
    for (int j = 0; j < 8; ++j) acc[i][j] = 0.f;

  const float* Ab = A + (size_t)bm * BM * K;
  const float* Bb = B + (size_t)bn * BN * K;

  for (int k0 = 0; k0 < K; k0 += BK) {
    // Stage tiles: 128x16 each = 512 float4s; 256 threads x 2.
#pragma unroll
    for (int r = 0; r < 2; ++r) {
      int e = tid + r * 256;
      int row = e >> 2;           // 0..127
      int col = (e & 3) << 2;     // 0,4,8,12
      float4 av = *(const float4*)(Ab + (size_t)row * K + k0 + col);
      As[col + 0][row] = av.x; As[col + 1][row] = av.y;
      As[col + 2][row] = av.z; As[col + 3][row] = av.w;
      float4 bv = *(const float4*)(Bb + (size_t)row * K + k0 + col);
      Bs[col + 0][row] = bv.x; Bs[col + 1][row] = bv.y;
      Bs[col + 2][row] = bv.z; Bs[col + 3][row] = bv.w;
    }
    __syncthreads();
#pragma unroll
    for (int k = 0; k < BK; ++k) {
      float a[8], b[8];
      *(float4*)&a[0] = *(const float4*)&As[k][ty * 8];
      *(float4*)&a[4] = *(const float4*)&As[k][ty * 8 + 4];
      *(float4*)&b[0] = *(const float4*)&Bs[k][tx * 8];
      *(float4*)&b[4] = *(const float4*)&Bs[k][tx * 8 + 4];
#pragma unroll
      for (int i = 0; i < 8; ++i)
#pragma unroll
        for (int j = 0; j < 8; ++j)
          acc[i][j] = fmaf(a[i], b[j], acc[i][j]);
    }
    __syncthreads();
  }

#pragma unroll
  for (int i = 0; i < 8; ++i) {
    int row = bm * BM + ty * 8 + i;
    int col0 = bn * BN + tx * 8;
    float* Cp = C + (size_t)row * N + col0;
    if (bias) {
#pragma unroll
      for (int j = 0; j < 8; ++j) acc[i][j] += bias[col0 + j];
    }
    *(float4*)(Cp) = *(float4*)&acc[i][0];
    *(float4*)(Cp + 4) = *(float4*)&acc[i][4];
  }
}

// ---------------------------------------------------------------------------
// Attention core: one block per (batch-local b, head h).
// sim[i][j] = scale * q[i]·(k[j] + rel_k[j-i+16])
// out[i][d] = sum_j softmax(sim)[i][j] * (v[j][d] + rel_v[j-i+16][d])
// LDS rows padded to 65 -> conflict-free access patterns.
// ---------------------------------------------------------------------------
__global__ __launch_bounds__(256)
void attn_kernel(const float* __restrict__ Q, const float* __restrict__ K,
                 const float* __restrict__ V,
                 const float* __restrict__ relk, const float* __restrict__ relv,
                 float* __restrict__ O) {
  __shared__ float qs[16][65], ks[16][65], vs[16][65];
  __shared__ float rk[33][65], rv[33][65];
  __shared__ float at[16][17];

  const int tid = threadIdx.x;
  const int bh = blockIdx.x;
  const int b = bh >> 4;   // batch index local to chunk
  const int h = bh & 15;
  const size_t base = (size_t)(b * T_SEQ) * D_MODEL + h * DIM_HEAD;

  for (int idx = tid; idx < T_SEQ * DIM_HEAD; idx += 256) {
    int r = idx >> 6, c = idx & 63;
    size_t g = base + (size_t)r * D_MODEL + c;
    qs[r][c] = Q[g]; ks[r][c] = K[g]; vs[r][c] = V[g];
  }
  for (int idx = tid; idx < 33 * DIM_HEAD; idx += 256) {
    int r = idx >> 6, c = idx & 63;
    rk[r][c] = relk[idx]; rv[r][c] = relv[idx];
  }
  __syncthreads();

  // scores: thread (i,j), i = tid/16, j = tid%16 (16-thread row groups)
  {
    const int i = tid >> 4, j = tid & 15;
    const int ridx = j - i + MAX_REL;   // in [1,31], no clipping needed (T=16)
    float s = 0.f;
#pragma unroll
    for (int d = 0; d < DIM_HEAD; ++d)
      s += qs[i][d] * (ks[j][d] + rk[ridx][d]);
    s *= 0.125f;  // dh^-0.5

    float m = s;
#pragma unroll
    for (int w = 8; w >= 1; w >>= 1) m = fmaxf(m, __shfl_xor(m, w, 16));
    float e = __expf(s - m);
    float sum = e;
#pragma unroll
    for (int w = 8; w >= 1; w >>= 1) sum += __shfl_xor(sum, w, 16);
    at[i][j] = e / sum;
  }
  __syncthreads();

  // output: thread handles (i2, d) pairs; d = tid%64, i2 = tid/64 + 4r
  const int d = tid & 63;
#pragma unroll
  for (int r = 0; r < 4; ++r) {
    int i2 = (tid >> 6) + r * 4;
    float acc = 0.f;
#pragma unroll
    for (int jj = 0; jj < 16; ++jj)
      acc += at[i2][jj] * (vs[jj][d] + rv[jj - i2 + MAX_REL][d]);
    O[base + (size_t)i2 * D_MODEL + d] = acc;
  }
}

// ---------------------------------------------------------------------------
extern "C" void kernel_launch(void* const* d_in, const int* in_sizes, int n_in,
                              void* d_out, int out_size, void* d_ws, size_t ws_size,
                              hipStream_t stream) {
  const float* x  = (const float*)d_in[0];
  const float* Wq = (const float*)d_in[1];
  const float* Wk = (const float*)d_in[2];
  const float* Wv = (const float*)d_in[3];
  const float* Wo = (const float*)d_in[4];
  const float* bo = (const float*)d_in[5];
  const float* rk = (const float*)d_in[6];
  const float* rv = (const float*)d_in[7];
  float* out = (float*)d_out;

  const int total_rows = 2048 * T_SEQ;  // 32768
  const size_t per_row_bytes = (size_t)4 * D_MODEL * sizeof(float);  // Q,K,V,AO

  // Chunk rows so 4 fp32 buffers of rows_c x 1024 fit in workspace.
  size_t rows_fit = ws_size / per_row_bytes;
  int rows_c = (rows_fit > (size_t)total_rows) ? total_rows : (int)rows_fit;
  rows_c = (rows_c / BM) * BM;
  if (rows_c < BM) rows_c = BM;  // minimum viable chunk (2 MB workspace)

  for (int r0 = 0; r0 < total_rows; r0 += rows_c) {
    int rc = total_rows - r0;
    if (rc > rows_c) rc = rows_c;

    float* Qb = (float*)d_ws;
    float* Kb = Qb + (size_t)rows_c * D_MODEL;
    float* Vb = Kb + (size_t)rows_c * D_MODEL;
    float* AO = Vb + (size_t)rows_c * D_MODEL;
    const float* xc = x + (size_t)r0 * D_MODEL;

    dim3 g(D_MODEL / BN, rc / BM);
    gemm_xwt<<<g, 256, 0, stream>>>(xc, Wq, nullptr, Qb, rc, D_MODEL, D_MODEL);
    gemm_xwt<<<g, 256, 0, stream>>>(xc, Wk, nullptr, Kb, rc, D_MODEL, D_MODEL);
    gemm_xwt<<<g, 256, 0, stream>>>(xc, Wv, nullptr, Vb, rc, D_MODEL, D_MODEL);

    // one block per (batch, head): rc/16 batches * 16 heads = rc blocks
    attn_kernel<<<rc, 256, 0, stream>>>(Qb, Kb, Vb, rk, rv, AO);

    gemm_xwt<<<g, 256, 0, stream>>>(AO, Wo, bo, out + (size_t)r0 * D_MODEL,
                                    rc, D_MODEL, D_MODEL);
  }
}

// Round 2
// 694.367 us; speedup vs baseline: 4.9284x; 4.9284x over previous
//
#include <hip/hip_runtime.h>

#define HEADS 16
#define DIM_HEAD 64
#define T_SEQ 16
#define D_MODEL 1024
#define MAX_REL 16

typedef _Float16 half8 __attribute__((ext_vector_type(8)));
typedef float f32x4 __attribute__((ext_vector_type(4)));

// ---------------------------------------------------------------------------
// fp32 -> fp16 conversion, 8 elems/thread
// ---------------------------------------------------------------------------
__global__ __launch_bounds__(256)
void cvt_f32_f16(const float* __restrict__ in, _Float16* __restrict__ out, int n8) {
  int i = blockIdx.x * blockDim.x + threadIdx.x;
  if (i >= n8) return;
  float4 a = ((const float4*)in)[2 * i];
  float4 b = ((const float4*)in)[2 * i + 1];
  half8 h;
  h[0] = (_Float16)a.x; h[1] = (_Float16)a.y;
  h[2] = (_Float16)a.z; h[3] = (_Float16)a.w;
  h[4] = (_Float16)b.x; h[5] = (_Float16)b.y;
  h[6] = (_Float16)b.z; h[7] = (_Float16)b.w;
  ((half8*)out)[i] = h;
}

// ---------------------------------------------------------------------------
// async global -> LDS, 16B per lane (dest = wave-uniform base + lane*16)
// ---------------------------------------------------------------------------
__device__ __forceinline__ void gload_lds16(const _Float16* g, _Float16* l) {
  __builtin_amdgcn_global_load_lds(
      (const __attribute__((address_space(1))) unsigned int*)(uintptr_t)g,
      (__attribute__((address_space(3))) unsigned int*)(uintptr_t)l, 16, 0, 0);
}

// ---------------------------------------------------------------------------
// MFMA fp16 GEMM: C[M,N] = A[M,K] * B[N,K]^T.  128x128 tile, BK=32,
// 4 waves, each wave 64x64 (4x4 frags of 16x16x32). m97-ladder structure.
// OUT_F16: C written as fp16. else: fp32 + bias.
// ---------------------------------------------------------------------------
template <bool OUT_F16>
__global__ __launch_bounds__(256)
void gemm_f16(const _Float16* __restrict__ A, const _Float16* __restrict__ B,
              const float* __restrict__ bias, void* __restrict__ Cv,
              int M, int N, int K) {
  __shared__ _Float16 As[128 * 32];
  __shared__ _Float16 Bs[128 * 32];
  const int tid = threadIdx.x;
  const int wave = tid >> 6, lane = tid & 63;
  const int bm = blockIdx.y, bn = blockIdx.x;

  const _Float16* Ag = A + (size_t)bm * 128 * K;
  const _Float16* Bg = B + (size_t)bn * 128 * K;

  const int srow = lane >> 2;        // 0..15 staging row within 16-row group
  const int scol = (lane & 3) * 8;   // f16 offset (16B chunks) within 64B row

  f32x4 acc[4][4];
#pragma unroll
  for (int m = 0; m < 4; ++m)
#pragma unroll
    for (int n = 0; n < 4; ++n) acc[m][n] = (f32x4){0.f, 0.f, 0.f, 0.f};

  const int mb = (wave >> 1) * 64, nb = (wave & 1) * 64;
  const int fr = lane & 15;          // frag row/col
  const int fk = (lane >> 4) * 8;    // frag k-base

  for (int k0 = 0; k0 < K; k0 += 32) {
#pragma unroll
    for (int i = 0; i < 2; ++i) {
      int r0 = wave * 16 + i * 64;   // 16-row group this wave stages
      gload_lds16(Ag + (size_t)(r0 + srow) * K + k0 + scol, As + r0 * 32);
      gload_lds16(Bg + (size_t)(r0 + srow) * K + k0 + scol, Bs + r0 * 32);
    }
    __syncthreads();

    half8 aF[4], bF[4];
#pragma unroll
    for (int m = 0; m < 4; ++m)
      aF[m] = *(const half8*)(As + (mb + m * 16 + fr) * 32 + fk);
#pragma unroll
    for (int n = 0; n < 4; ++n)
      bF[n] = *(const half8*)(Bs + (nb + n * 16 + fr) * 32 + fk);
#pragma unroll
    for (int m = 0; m < 4; ++m)
#pragma unroll
      for (int n = 0; n < 4; ++n)
        acc[m][n] = __builtin_amdgcn_mfma_f32_16x16x32_f16(aF[m], bF[n],
                                                           acc[m][n], 0, 0, 0);
    __syncthreads();
  }

  const int col_l = lane & 15, row_l = (lane >> 4) * 4;
#pragma unroll
  for (int m = 0; m < 4; ++m) {
#pragma unroll
    for (int n = 0; n < 4; ++n) {
      int col = bn * 128 + nb + n * 16 + col_l;
#pragma unroll
      for (int r = 0; r < 4; ++r) {
        int row = bm * 128 + mb + m * 16 + row_l + r;
        if (OUT_F16) {
          ((_Float16*)Cv)[(size_t)row * N + col] = (_Float16)acc[m][n][r];
        } else {
          ((float*)Cv)[(size_t)row * N + col] = acc[m][n][r] + bias[col];
        }
      }
    }
  }
}

// ---------------------------------------------------------------------------
// Attention core (fp16 I/O, fp32 math). One block per (batch-local b, head h).
// ---------------------------------------------------------------------------
__global__ __launch_bounds__(256)
void attn_f16(const _Float16* __restrict__ Q, const _Float16* __restrict__ K,
              const _Float16* __restrict__ V,
              const float* __restrict__ relk, const float* __restrict__ relv,
              _Float16* __restrict__ O) {
  __shared__ float qs[16][65], ks[16][65], vs[16][65];
  __shared__ float rk[33][65], rv[33][65];
  __shared__ float at[16][17];

  const int tid = threadIdx.x;
  const int bh = blockIdx.x;
  const int b = bh >> 4;
  const int h = bh & 15;
  const size_t base = (size_t)(b * T_SEQ) * D_MODEL + h * DIM_HEAD;

  if (tid < 128) {  // 16 rows x 64 cols / 8 per thread
    int r = tid >> 3, c8 = (tid & 7) * 8;
    size_t g = base + (size_t)r * D_MODEL + c8;
    half8 q8 = *(const half8*)(Q + g);
    half8 k8 = *(const half8*)(K + g);
    half8 v8 = *(const half8*)(V + g);
#pragma unroll
    for (int e = 0; e < 8; ++e) {
      qs[r][c8 + e] = (float)q8[e];
      ks[r][c8 + e] = (float)k8[e];
      vs[r][c8 + e] = (float)v8[e];
    }
  }
  for (int idx = tid; idx < 33 * DIM_HEAD; idx += 256) {
    int r = idx >> 6, c = idx & 63;
    rk[r][c] = relk[idx]; rv[r][c] = relv[idx];
  }
  __syncthreads();

  {
    const int i = tid >> 4, j = tid & 15;
    const int ridx = j - i + MAX_REL;
    float s = 0.f;
#pragma unroll
    for (int d = 0; d < DIM_HEAD; ++d)
      s += qs[i][d] * (ks[j][d] + rk[ridx][d]);
    s *= 0.125f;

    float m = s;
#pragma unroll
    for (int w = 8; w >= 1; w >>= 1) m = fmaxf(m, __shfl_xor(m, w, 16));
    float e = __expf(s - m);
    float sum = e;
#pragma unroll
    for (int w = 8; w >= 1; w >>= 1) sum += __shfl_xor(sum, w, 16);
    at[i][j] = e / sum;
  }
  __syncthreads();

  const int d = tid & 63;
#pragma unroll
  for (int r = 0; r < 4; ++r) {
    int i2 = (tid >> 6) + r * 4;
    float acc = 0.f;
#pragma unroll
    for (int jj = 0; jj < 16; ++jj)
      acc += at[i2][jj] * (vs[jj][d] + rv[jj - i2 + MAX_REL][d]);
    O[base + (size_t)i2 * D_MODEL + d] = (_Float16)acc;
  }
}

// ---------------------------------------------------------------------------
extern "C" void kernel_launch(void* const* d_in, const int* in_sizes, int n_in,
                              void* d_out, int out_size, void* d_ws, size_t ws_size,
                              hipStream_t stream) {
  const float* x  = (const float*)d_in[0];
  const float* Wq = (const float*)d_in[1];
  const float* Wk = (const float*)d_in[2];
  const float* Wv = (const float*)d_in[3];
  const float* Wo = (const float*)d_in[4];
  const float* bo = (const float*)d_in[5];
  const float* rk = (const float*)d_in[6];
  const float* rv = (const float*)d_in[7];
  float* out = (float*)d_out;

  const int total_rows = 2048 * T_SEQ;           // 32768
  const size_t wsz = (size_t)D_MODEL * D_MODEL;  // 1M elems per weight

  // workspace: 4 fp16 weights, then per-chunk fp16 buffers
  _Float16* Wqh = (_Float16*)d_ws;
  _Float16* Wkh = Wqh + wsz;
  _Float16* Wvh = Wkh + wsz;
  _Float16* Woh = Wvh + wsz;
  _Float16* chunk_base = Woh + wsz;

  // convert weights (1M elems each -> 131072 x half8)
  {
    int n8 = (int)(wsz / 8);
    int blocks = (n8 + 255) / 256;
    cvt_f32_f16<<<blocks, 256, 0, stream>>>(Wq, Wqh, n8);
    cvt_f32_f16<<<blocks, 256, 0, stream>>>(Wk, Wkh, n8);
    cvt_f32_f16<<<blocks, 256, 0, stream>>>(Wv, Wvh, n8);
    cvt_f32_f16<<<blocks, 256, 0, stream>>>(Wo, Woh, n8);
  }

  // chunk rows: 5 fp16 buffers (xh,Q,K,V,AO) of rows_c x 1024
  const size_t per_row_bytes = (size_t)5 * D_MODEL * sizeof(_Float16);
  size_t avail = ws_size - (size_t)4 * wsz * sizeof(_Float16);
  size_t rows_fit = avail / per_row_bytes;
  int rows_c = (rows_fit > (size_t)total_rows) ? total_rows : (int)rows_fit;
  rows_c = (rows_c / 128) * 128;
  if (rows_c < 128) rows_c = 128;

  for (int r0 = 0; r0 < total_rows; r0 += rows_c) {
    int rc = total_rows - r0;
    if (rc > rows_c) rc = rows_c;

    _Float16* xh = chunk_base;
    _Float16* Qh = xh + (size_t)rows_c * D_MODEL;
    _Float16* Kh = Qh + (size_t)rows_c * D_MODEL;
    _Float16* Vh = Kh + (size_t)rows_c * D_MODEL;
    _Float16* AO = Vh + (size_t)rows_c * D_MODEL;

    {
      int n8 = rc * D_MODEL / 8;
      cvt_f32_f16<<<(n8 + 255) / 256, 256, 0, stream>>>(
          x + (size_t)r0 * D_MODEL, xh, n8);
    }

    dim3 g(D_MODEL / 128, rc / 128);
    gemm_f16<true><<<g, 256, 0, stream>>>(xh, Wqh, nullptr, Qh, rc, D_MODEL, D_MODEL);
    gemm_f16<true><<<g, 256, 0, stream>>>(xh, Wkh, nullptr, Kh, rc, D_MODEL, D_MODEL);
    gemm_f16<true><<<g, 256, 0, stream>>>(xh, Wvh, nullptr, Vh, rc, D_MODEL, D_MODEL);

    attn_f16<<<rc, 256, 0, stream>>>(Qh, Kh, Vh, rk, rv, AO);

    gemm_f16<false><<<g, 256, 0, stream>>>(AO, Woh, bo, out + (size_t)r0 * D_MODEL,
                                           rc, D_MODEL, D_MODEL);
  }
}

// Round 3
// 516.125 us; speedup vs baseline: 6.6305x; 1.3453x over previous
//
#include <hip/hip_runtime.h>

#define HEADS 16
#define DIM_HEAD 64
#define T_SEQ 16
#define D_MODEL 1024
#define MAX_REL 16

typedef _Float16 half8 __attribute__((ext_vector_type(8)));
typedef float f32x4 __attribute__((ext_vector_type(4)));

// ---------------------------------------------------------------------------
// fp32 -> fp16 conversion, 8 elems/thread
// ---------------------------------------------------------------------------
__global__ __launch_bounds__(256)
void cvt_f32_f16(const float* __restrict__ in, _Float16* __restrict__ out, int n8) {
  int i = blockIdx.x * blockDim.x + threadIdx.x;
  if (i >= n8) return;
  float4 a = ((const float4*)in)[2 * i];
  float4 b = ((const float4*)in)[2 * i + 1];
  half8 h;
  h[0] = (_Float16)a.x; h[1] = (_Float16)a.y;
  h[2] = (_Float16)a.z; h[3] = (_Float16)a.w;
  h[4] = (_Float16)b.x; h[5] = (_Float16)b.y;
  h[6] = (_Float16)b.z; h[7] = (_Float16)b.w;
  ((half8*)out)[i] = h;
}

// ---------------------------------------------------------------------------
// async global -> LDS, 16B per lane
// ---------------------------------------------------------------------------
__device__ __forceinline__ void gload_lds16(const _Float16* g, _Float16* l) {
  __builtin_amdgcn_global_load_lds(
      (const __attribute__((address_space(1))) unsigned int*)(uintptr_t)g,
      (__attribute__((address_space(3))) unsigned int*)(uintptr_t)l, 16, 0, 0);
}

// ---------------------------------------------------------------------------
// MFMA fp16 GEMM: C[M,N] = A[M,K] * B[N,K]^T.  128x128 tile, BK=32, 4 waves.
// ---------------------------------------------------------------------------
template <bool OUT_F16>
__global__ __launch_bounds__(256)
void gemm_f16(const _Float16* __restrict__ A, const _Float16* __restrict__ B,
              const float* __restrict__ bias, void* __restrict__ Cv,
              int M, int N, int K) {
  __shared__ _Float16 As[128 * 32];
  __shared__ _Float16 Bs[128 * 32];
  const int tid = threadIdx.x;
  const int wave = tid >> 6, lane = tid & 63;
  const int bm = blockIdx.y, bn = blockIdx.x;

  const _Float16* Ag = A + (size_t)bm * 128 * K;
  const _Float16* Bg = B + (size_t)bn * 128 * K;

  const int srow = lane >> 2;
  const int scol = (lane & 3) * 8;

  f32x4 acc[4][4];
#pragma unroll
  for (int m = 0; m < 4; ++m)
#pragma unroll
    for (int n = 0; n < 4; ++n) acc[m][n] = (f32x4){0.f, 0.f, 0.f, 0.f};

  const int mb = (wave >> 1) * 64, nb = (wave & 1) * 64;
  const int fr = lane & 15;
  const int fk = (lane >> 4) * 8;

  for (int k0 = 0; k0 < K; k0 += 32) {
#pragma unroll
    for (int i = 0; i < 2; ++i) {
      int r0 = wave * 16 + i * 64;
      gload_lds16(Ag + (size_t)(r0 + srow) * K + k0 + scol, As + r0 * 32);
      gload_lds16(Bg + (size_t)(r0 + srow) * K + k0 + scol, Bs + r0 * 32);
    }
    __syncthreads();

    half8 aF[4], bF[4];
#pragma unroll
    for (int m = 0; m < 4; ++m)
      aF[m] = *(const half8*)(As + (mb + m * 16 + fr) * 32 + fk);
#pragma unroll
    for (int n = 0; n < 4; ++n)
      bF[n] = *(const half8*)(Bs + (nb + n * 16 + fr) * 32 + fk);
#pragma unroll
    for (int m = 0; m < 4; ++m)
#pragma unroll
      for (int n = 0; n < 4; ++n)
        acc[m][n] = __builtin_amdgcn_mfma_f32_16x16x32_f16(aF[m], bF[n],
                                                           acc[m][n], 0, 0, 0);
    __syncthreads();
  }

  const int col_l = lane & 15, row_l = (lane >> 4) * 4;
#pragma unroll
  for (int m = 0; m < 4; ++m) {
#pragma unroll
    for (int n = 0; n < 4; ++n) {
      int col = bn * 128 + nb + n * 16 + col_l;
#pragma unroll
      for (int r = 0; r < 4; ++r) {
        int row = bm * 128 + mb + m * 16 + row_l + r;
        if (OUT_F16) {
          ((_Float16*)Cv)[(size_t)row * N + col] = (_Float16)acc[m][n][r];
        } else {
          ((float*)Cv)[(size_t)row * N + col] = acc[m][n][r] + bias[col];
        }
      }
    }
  }
}

// ---------------------------------------------------------------------------
// MFMA attention: one wave per head, 4 heads per block.
// QKV: [rows][3072] fp16 (Q cols 0-1023, K 1024-2047, V 2048-3071)
// O:   [rows][1024] fp16
// Per head (T=16, dh=64):
//   S  = Q K^T                    (2x mfma 16x16x32)
//   G  = Q RK^T  [16][32]         (4x mfma)
//   sim = (S + gather(G))*scale ; softmax in-register (16-lane groups)
//   out = [P|0|B2] x [V^T|0|RV^T] (8x mfma)  where B2[i][m]=P[i][m+i-16]
// ---------------------------------------------------------------------------
__global__ __launch_bounds__(256)
void attn_mfma(const _Float16* __restrict__ QKV,
               const float* __restrict__ relk, const float* __restrict__ relv,
               _Float16* __restrict__ O) {
  __shared__ _Float16 RK[32][72];        // rel_k rows 0..31, row-major
  __shared__ _Float16 RVt[64][40];       // RVt[d][m] = rel_v[m][d]
  __shared__ _Float16 PB[4][16][72];     // [P(0:16) | zero(16:32) | B2(32:64)]
  __shared__ _Float16 VtP[4][64][40];    // [V^T(0:16) | zero(16:32)]

  const int tid = threadIdx.x;
  const int wave = tid >> 6, lane = tid & 63;

  // ---- block-level staging of rel tables (fp32 -> fp16, RV transposed) ----
  {
    int m = tid >> 3;                 // 0..31
    int d0 = (tid & 7) * 8;           // 0..56
    float4 a = *(const float4*)(relk + m * 64 + d0);
    float4 b = *(const float4*)(relk + m * 64 + d0 + 4);
    half8 hk;
    hk[0] = (_Float16)a.x; hk[1] = (_Float16)a.y;
    hk[2] = (_Float16)a.z; hk[3] = (_Float16)a.w;
    hk[4] = (_Float16)b.x; hk[5] = (_Float16)b.y;
    hk[6] = (_Float16)b.z; hk[7] = (_Float16)b.w;
    *(half8*)&RK[m][d0] = hk;
    float4 c = *(const float4*)(relv + m * 64 + d0);
    float4 d = *(const float4*)(relv + m * 64 + d0 + 4);
    RVt[d0 + 0][m] = (_Float16)c.x; RVt[d0 + 1][m] = (_Float16)c.y;
    RVt[d0 + 2][m] = (_Float16)c.z; RVt[d0 + 3][m] = (_Float16)c.w;
    RVt[d0 + 4][m] = (_Float16)d.x; RVt[d0 + 5][m] = (_Float16)d.y;
    RVt[d0 + 6][m] = (_Float16)d.z; RVt[d0 + 7][m] = (_Float16)d.w;
  }

  // ---- per-wave zero-init of padded regions ----
#pragma unroll
  for (int z = 0; z < 6; ++z) {       // PB cols 16..63 : 16 rows x 24 dwords
    int idx = z * 64 + lane;
    int row = idx / 24, cd = idx % 24;
    *(unsigned int*)&PB[wave][row][16 + 2 * cd] = 0u;
  }
#pragma unroll
  for (int z = 0; z < 8; ++z) {       // VtP cols 16..31 : 64 rows x 8 dwords
    int idx = z * 64 + lane;
    int row = idx >> 3, cd = idx & 7;
    *(unsigned int*)&VtP[wave][row][16 + 2 * cd] = 0u;
  }

  const int bh = blockIdx.x * 4 + wave;
  const int b = bh >> 4, h = bh & 15;
  const size_t qbase = (size_t)(b * T_SEQ) * 3072 + h * 64;
  const int fr = lane & 15, fk8 = (lane >> 4) * 8;

  // ---- load Q/K fragments straight from global (A/B layout == row-major) --
  half8 aQ0 = *(const half8*)(QKV + qbase + (size_t)fr * 3072 + fk8);
  half8 aQ1 = *(const half8*)(QKV + qbase + (size_t)fr * 3072 + 32 + fk8);
  half8 bK0 = *(const half8*)(QKV + qbase + 1024 + (size_t)fr * 3072 + fk8);
  half8 bK1 = *(const half8*)(QKV + qbase + 1024 + (size_t)fr * 3072 + 32 + fk8);

  // ---- stage V transposed into VtP[d][j] ----
  {
    const _Float16* vp = QKV + qbase + 2048 + (size_t)fr * 3072 + (lane >> 4) * 16;
    half8 v0 = *(const half8*)vp;
    half8 v1 = *(const half8*)(vp + 8);
    int d0 = (lane >> 4) * 16;
#pragma unroll
    for (int e = 0; e < 8; ++e) VtP[wave][d0 + e][fr] = v0[e];
#pragma unroll
    for (int e = 0; e < 8; ++e) VtP[wave][d0 + 8 + e][fr] = v1[e];
  }

  __syncthreads();   // RK / RVt ready

  // ---- S and G MFMAs ----
  f32x4 accS = {0.f, 0.f, 0.f, 0.f};
  accS = __builtin_amdgcn_mfma_f32_16x16x32_f16(aQ0, bK0, accS, 0, 0, 0);
  accS = __builtin_amdgcn_mfma_f32_16x16x32_f16(aQ1, bK1, accS, 0, 0, 0);

  half8 rk0a = *(const half8*)&RK[fr][fk8];
  half8 rk0b = *(const half8*)&RK[fr][32 + fk8];
  half8 rk1a = *(const half8*)&RK[16 + fr][fk8];
  half8 rk1b = *(const half8*)&RK[16 + fr][32 + fk8];
  f32x4 G0 = {0.f, 0.f, 0.f, 0.f}, G1 = {0.f, 0.f, 0.f, 0.f};
  G0 = __builtin_amdgcn_mfma_f32_16x16x32_f16(aQ0, rk0a, G0, 0, 0, 0);
  G0 = __builtin_amdgcn_mfma_f32_16x16x32_f16(aQ1, rk0b, G0, 0, 0, 0);
  G1 = __builtin_amdgcn_mfma_f32_16x16x32_f16(aQ0, rk1a, G1, 0, 0, 0);
  G1 = __builtin_amdgcn_mfma_f32_16x16x32_f16(aQ1, rk1b, G1, 0, 0, 0);

  // ---- gather rel-bias, softmax (rows live across 16-lane groups) ----
  const int ibase = (lane >> 4) * 4;
#pragma unroll
  for (int r = 0; r < 4; ++r) {
    const int i = ibase + r;
    const int ridx = fr - i + MAX_REL;          // in [1,31]
    const int src = (lane & 48) | (ridx & 15);
    float g0 = __shfl(G0[r], src);
    float g1 = __shfl(G1[r], src);
    float g = (ridx >= 16) ? g1 : g0;
    float s = (accS[r] + g) * 0.125f;
    float mx = s;
#pragma unroll
    for (int w = 8; w >= 1; w >>= 1) mx = fmaxf(mx, __shfl_xor(mx, w));
    float e = __expf(s - mx);
    float sum = e;
#pragma unroll
    for (int w = 8; w >= 1; w >>= 1) sum += __shfl_xor(sum, w);
    _Float16 ph = (_Float16)(e / sum);
    PB[wave][i][fr] = ph;                        // P
    PB[wave][i][32 + (fr - i + MAX_REL)] = ph;   // B2 scatter (cols 33..63)
  }

  // ---- output: [P|0|B2] x [Vt|0 ; RVt] ----
  half8 aP0 = *(const half8*)&PB[wave][fr][fk8];        // K 0..31
  half8 aP1 = *(const half8*)&PB[wave][fr][32 + fk8];   // K 32..63
  const size_t obase = (size_t)(b * T_SEQ) * D_MODEL + h * 64;
#pragma unroll
  for (int t = 0; t < 4; ++t) {
    half8 bv = *(const half8*)&VtP[wave][t * 16 + fr][fk8];
    half8 br = *(const half8*)&RVt[t * 16 + fr][fk8];
    f32x4 o = {0.f, 0.f, 0.f, 0.f};
    o = __builtin_amdgcn_mfma_f32_16x16x32_f16(aP0, bv, o, 0, 0, 0);
    o = __builtin_amdgcn_mfma_f32_16x16x32_f16(aP1, br, o, 0, 0, 0);
#pragma unroll
    for (int r = 0; r < 4; ++r)
      O[obase + (size_t)(ibase + r) * D_MODEL + t * 16 + fr] = (_Float16)o[r];
  }
}

// ---------------------------------------------------------------------------
extern "C" void kernel_launch(void* const* d_in, const int* in_sizes, int n_in,
                              void* d_out, int out_size, void* d_ws, size_t ws_size,
                              hipStream_t stream) {
  const float* x  = (const float*)d_in[0];
  const float* Wq = (const float*)d_in[1];
  const float* Wk = (const float*)d_in[2];
  const float* Wv = (const float*)d_in[3];
  const float* Wo = (const float*)d_in[4];
  const float* bo = (const float*)d_in[5];
  const float* rk = (const float*)d_in[6];
  const float* rv = (const float*)d_in[7];
  float* out = (float*)d_out;

  const int total_rows = 2048 * T_SEQ;           // 32768
  const size_t wsz = (size_t)D_MODEL * D_MODEL;  // 1M elems per weight

  // workspace: Wqkv (3M f16) + Wo (1M f16), then per-chunk buffers
  _Float16* Wqkvh = (_Float16*)d_ws;
  _Float16* Woh = Wqkvh + 3 * wsz;
  _Float16* chunk_base = Woh + wsz;

  {
    int n8 = (int)(wsz / 8);
    int blocks = (n8 + 255) / 256;
    cvt_f32_f16<<<blocks, 256, 0, stream>>>(Wq, Wqkvh, n8);
    cvt_f32_f16<<<blocks, 256, 0, stream>>>(Wk, Wqkvh + wsz, n8);
    cvt_f32_f16<<<blocks, 256, 0, stream>>>(Wv, Wqkvh + 2 * wsz, n8);
    cvt_f32_f16<<<blocks, 256, 0, stream>>>(Wo, Woh, n8);
  }

  // per-chunk: xh (1024) + QKV (3072) + AO (1024) fp16 per row
  const size_t per_row_bytes = (size_t)5120 * sizeof(_Float16);
  size_t avail = ws_size - (size_t)4 * wsz * sizeof(_Float16);
  size_t rows_fit = avail / per_row_bytes;
  int rows_c = (rows_fit > (size_t)total_rows) ? total_rows : (int)rows_fit;
  rows_c = (rows_c / 128) * 128;
  if (rows_c < 128) rows_c = 128;

  for (int r0 = 0; r0 < total_rows; r0 += rows_c) {
    int rc = total_rows - r0;
    if (rc > rows_c) rc = rows_c;

    _Float16* xh   = chunk_base;
    _Float16* QKVb = xh + (size_t)rows_c * 1024;
    _Float16* AO   = QKVb + (size_t)rows_c * 3072;

    {
      int n8 = rc * 128;
      cvt_f32_f16<<<(n8 + 255) / 256, 256, 0, stream>>>(
          x + (size_t)r0 * D_MODEL, xh, n8);
    }

    dim3 g1(3072 / 128, rc / 128);
    gemm_f16<true><<<g1, 256, 0, stream>>>(xh, Wqkvh, nullptr, QKVb,
                                           rc, 3072, 1024);

    attn_mfma<<<rc / 4, 256, 0, stream>>>(QKVb, rk, rv, AO);

    dim3 g2(1024 / 128, rc / 128);
    gemm_f16<false><<<g2, 256, 0, stream>>>(AO, Woh, bo, out + (size_t)r0 * D_MODEL,
                                            rc, 1024, 1024);
  }
}

// Round 4
// 417.327 us; speedup vs baseline: 8.2002x; 1.2367x over previous
//
#include <hip/hip_runtime.h>

#define HEADS 16
#define DIM_HEAD 64
#define T_SEQ 16
#define D_MODEL 1024
#define MAX_REL 16

typedef _Float16 half8 __attribute__((ext_vector_type(8)));
typedef float f32x4 __attribute__((ext_vector_type(4)));

// ---------------------------------------------------------------------------
// fp32 -> fp16 conversion, 8 elems/thread
// ---------------------------------------------------------------------------
__global__ __launch_bounds__(256)
void cvt_f32_f16(const float* __restrict__ in, _Float16* __restrict__ out, int n8) {
  int i = blockIdx.x * blockDim.x + threadIdx.x;
  if (i >= n8) return;
  float4 a = ((const float4*)in)[2 * i];
  float4 b = ((const float4*)in)[2 * i + 1];
  half8 h;
  h[0] = (_Float16)a.x; h[1] = (_Float16)a.y;
  h[2] = (_Float16)a.z; h[3] = (_Float16)a.w;
  h[4] = (_Float16)b.x; h[5] = (_Float16)b.y;
  h[6] = (_Float16)b.z; h[7] = (_Float16)b.w;
  ((half8*)out)[i] = h;
}

// ---------------------------------------------------------------------------
// async global -> LDS, 16B per lane (dest = wave-uniform base + lane*16)
// ---------------------------------------------------------------------------
__device__ __forceinline__ void gload_lds16(const _Float16* g, _Float16* l) {
  __builtin_amdgcn_global_load_lds(
      (const __attribute__((address_space(1))) unsigned int*)(uintptr_t)g,
      (__attribute__((address_space(3))) unsigned int*)(uintptr_t)l, 16, 0, 0);
}

// ---------------------------------------------------------------------------
// 256x256 MFMA fp16 GEMM, BK=64, 8 waves (2M x 4N), phase-split pipeline.
// C[M,N] = A[M,K]*B[N,K]^T. LDS [buf][A/B][half][128][64] fp16 = 128 KB,
// XOR-swizzled slots: phys_slot = logical_slot ^ (row&7) (16B slots).
// Staged via global_load_lds with pre-swizzled global source.
// ---------------------------------------------------------------------------
template <bool OUT_F16>
__global__ __launch_bounds__(512, 2)
void gemm256(const _Float16* __restrict__ A, const _Float16* __restrict__ B,
             const float* __restrict__ bias, void* __restrict__ Cv,
             int M, int N, int K) {
  __shared__ _Float16 lds[2][2][2][128][64];
  const int tid = threadIdx.x;
  const int wave = tid >> 6, lane = tid & 63;
  const int wm = wave >> 2, wn = wave & 3;
  const int bm = blockIdx.y, bn = blockIdx.x;
  const int fr = lane & 15;          // frag row/col within 16
  const int q4 = lane >> 4;          // 0..3 : 16B slot within 64B k-half
  const int l3 = lane >> 3;          // staging row within 8-row group
  const int sl = (lane & 7) ^ l3;    // pre-swizzled source slot

  const _Float16* Ag = A + (size_t)(bm * 256) * K;
  const _Float16* Bg = B + (size_t)(bn * 256) * K;

  f32x4 acc[8][4];
#pragma unroll
  for (int m = 0; m < 8; ++m)
#pragma unroll
    for (int n = 0; n < 4; ++n) acc[m][n] = (f32x4){0.f, 0.f, 0.f, 0.f};

  // stage one 128x64 half-tile (2 x gload_lds per thread)
  auto stage_half = [&](int buf, int ab, int half, const _Float16* G, int k0) {
#pragma unroll
    for (int i = 0; i < 2; ++i) {
      int g = wave * 2 + i;  // 8-row group 0..15
      const _Float16* src =
          G + (size_t)(half * 128 + g * 8 + l3) * K + k0 + sl * 8;
      gload_lds16(src, &lds[buf][ab][half][g * 8][0]);
    }
  };

  auto ldA = [&](int buf, int mf, int ks) {
    unsigned off = (unsigned)((mf * 16 + fr) * 128 + (ks * 4 + q4) * 16) ^
                   (unsigned)((fr & 7) << 4);
    return *(const half8*)((const char*)&lds[buf][0][wm][0][0] + off);
  };
  auto ldB = [&](int buf, int nf, int ks) {
    int rowB = wn * 64 + nf * 16 + fr;
    unsigned off = (unsigned)((rowB & 127) * 128 + (ks * 4 + q4) * 16) ^
                   (unsigned)((fr & 7) << 4);
    return *(const half8*)((const char*)&lds[buf][1][rowB >> 7][0][0] + off);
  };

  // prologue: stage tile 0 fully
#pragma unroll
  for (int h = 0; h < 2; ++h) {
    stage_half(0, 0, h, Ag, 0);
    stage_half(0, 1, h, Bg, 0);
  }
  asm volatile("s_waitcnt vmcnt(0)" ::: "memory");
  __builtin_amdgcn_s_barrier();

  const int NT = K >> 6;
  for (int t = 0; t < NT; ++t) {
    const int cur = t & 1, nxt = cur ^ 1;
    const bool pf = (t + 1 < NT);
    const int k1 = (t + 1) << 6;
    half8 bF[4][2];
#pragma unroll
    for (int p = 0; p < 4; ++p) {
      // ---- region A: ds_reads for this phase's quadrant + 1 half-tile stage
      half8 aF[2][2];
#pragma unroll
      for (int i = 0; i < 2; ++i)
#pragma unroll
        for (int ks = 0; ks < 2; ++ks) aF[i][ks] = ldA(cur, p * 2 + i, ks);
      if (p == 0) {
#pragma unroll
        for (int nf = 0; nf < 4; ++nf)
#pragma unroll
          for (int ks = 0; ks < 2; ++ks) bF[nf][ks] = ldB(cur, nf, ks);
      }
      if (pf) {
        if (p < 2) stage_half(nxt, 0, p, Ag, k1);
        else       stage_half(nxt, 1, p - 2, Bg, k1);
      }
      __builtin_amdgcn_s_barrier();
      asm volatile("s_waitcnt lgkmcnt(0)" ::: "memory");
      __builtin_amdgcn_sched_barrier(0);
      // ---- region B: 16 MFMA (quadrant p x K=64)
      __builtin_amdgcn_s_setprio(1);
#pragma unroll
      for (int i = 0; i < 2; ++i)
#pragma unroll
        for (int nf = 0; nf < 4; ++nf)
#pragma unroll
          for (int ks = 0; ks < 2; ++ks)
            acc[p * 2 + i][nf] = __builtin_amdgcn_mfma_f32_16x16x32_f16(
                aF[i][ks], bF[nf][ks], acc[p * 2 + i][nf], 0, 0, 0);
      __builtin_amdgcn_s_setprio(0);
      __builtin_amdgcn_sched_barrier(0);
      if (p == 3) asm volatile("s_waitcnt vmcnt(0)" ::: "memory");
      __builtin_amdgcn_s_barrier();
    }
  }

  // ---- epilogue ----
  const int row_l = q4 * 4;
#pragma unroll
  for (int mf = 0; mf < 8; ++mf) {
#pragma unroll
    for (int nf = 0; nf < 4; ++nf) {
      int col = bn * 256 + wn * 64 + nf * 16 + fr;
#pragma unroll
      for (int r = 0; r < 4; ++r) {
        int row = bm * 256 + wm * 128 + mf * 16 + row_l + r;
        if (OUT_F16) {
          ((_Float16*)Cv)[(size_t)row * N + col] = (_Float16)acc[mf][nf][r];
        } else {
          ((float*)Cv)[(size_t)row * N + col] = acc[mf][nf][r] + bias[col];
        }
      }
    }
  }
}

// ---------------------------------------------------------------------------
// MFMA attention: one wave per head, 4 heads per block. (unchanged, passing)
// ---------------------------------------------------------------------------
__global__ __launch_bounds__(256)
void attn_mfma(const _Float16* __restrict__ QKV,
               const float* __restrict__ relk, const float* __restrict__ relv,
               _Float16* __restrict__ O) {
  __shared__ _Float16 RK[32][72];
  __shared__ _Float16 RVt[64][40];
  __shared__ _Float16 PB[4][16][72];
  __shared__ _Float16 VtP[4][64][40];

  const int tid = threadIdx.x;
  const int wave = tid >> 6, lane = tid & 63;

  {
    int m = tid >> 3;
    int d0 = (tid & 7) * 8;
    float4 a = *(const float4*)(relk + m * 64 + d0);
    float4 b = *(const float4*)(relk + m * 64 + d0 + 4);
    half8 hk;
    hk[0] = (_Float16)a.x; hk[1] = (_Float16)a.y;
    hk[2] = (_Float16)a.z; hk[3] = (_Float16)a.w;
    hk[4] = (_Float16)b.x; hk[5] = (_Float16)b.y;
    hk[6] = (_Float16)b.z; hk[7] = (_Float16)b.w;
    *(half8*)&RK[m][d0] = hk;
    float4 c = *(const float4*)(relv + m * 64 + d0);
    float4 d = *(const float4*)(relv + m * 64 + d0 + 4);
    RVt[d0 + 0][m] = (_Float16)c.x; RVt[d0 + 1][m] = (_Float16)c.y;
    RVt[d0 + 2][m] = (_Float16)c.z; RVt[d0 + 3][m] = (_Float16)c.w;
    RVt[d0 + 4][m] = (_Float16)d.x; RVt[d0 + 5][m] = (_Float16)d.y;
    RVt[d0 + 6][m] = (_Float16)d.z; RVt[d0 + 7][m] = (_Float16)d.w;
  }

#pragma unroll
  for (int z = 0; z < 6; ++z) {
    int idx = z * 64 + lane;
    int row = idx / 24, cd = idx % 24;
    *(unsigned int*)&PB[wave][row][16 + 2 * cd] = 0u;
  }
#pragma unroll
  for (int z = 0; z < 8; ++z) {
    int idx = z * 64 + lane;
    int row = idx >> 3, cd = idx & 7;
    *(unsigned int*)&VtP[wave][row][16 + 2 * cd] = 0u;
  }

  const int bh = blockIdx.x * 4 + wave;
  const int b = bh >> 4, h = bh & 15;
  const size_t qbase = (size_t)(b * T_SEQ) * 3072 + h * 64;
  const int fr = lane & 15, fk8 = (lane >> 4) * 8;

  half8 aQ0 = *(const half8*)(QKV + qbase + (size_t)fr * 3072 + fk8);
  half8 aQ1 = *(const half8*)(QKV + qbase + (size_t)fr * 3072 + 32 + fk8);
  half8 bK0 = *(const half8*)(QKV + qbase + 1024 + (size_t)fr * 3072 + fk8);
  half8 bK1 = *(const half8*)(QKV + qbase + 1024 + (size_t)fr * 3072 + 32 + fk8);

  {
    const _Float16* vp = QKV + qbase + 2048 + (size_t)fr * 3072 + (lane >> 4) * 16;
    half8 v0 = *(const half8*)vp;
    half8 v1 = *(const half8*)(vp + 8);
    int d0 = (lane >> 4) * 16;
#pragma unroll
    for (int e = 0; e < 8; ++e) VtP[wave][d0 + e][fr] = v0[e];
#pragma unroll
    for (int e = 0; e < 8; ++e) VtP[wave][d0 + 8 + e][fr] = v1[e];
  }

  __syncthreads();

  f32x4 accS = {0.f, 0.f, 0.f, 0.f};
  accS = __builtin_amdgcn_mfma_f32_16x16x32_f16(aQ0, bK0, accS, 0, 0, 0);
  accS = __builtin_amdgcn_mfma_f32_16x16x32_f16(aQ1, bK1, accS, 0, 0, 0);

  half8 rk0a = *(const half8*)&RK[fr][fk8];
  half8 rk0b = *(const half8*)&RK[fr][32 + fk8];
  half8 rk1a = *(const half8*)&RK[16 + fr][fk8];
  half8 rk1b = *(const half8*)&RK[16 + fr][32 + fk8];
  f32x4 G0 = {0.f, 0.f, 0.f, 0.f}, G1 = {0.f, 0.f, 0.f, 0.f};
  G0 = __builtin_amdgcn_mfma_f32_16x16x32_f16(aQ0, rk0a, G0, 0, 0, 0);
  G0 = __builtin_amdgcn_mfma_f32_16x16x32_f16(aQ1, rk0b, G0, 0, 0, 0);
  G1 = __builtin_amdgcn_mfma_f32_16x16x32_f16(aQ0, rk1a, G1, 0, 0, 0);
  G1 = __builtin_amdgcn_mfma_f32_16x16x32_f16(aQ1, rk1b, G1, 0, 0, 0);

  const int ibase = (lane >> 4) * 4;
#pragma unroll
  for (int r = 0; r < 4; ++r) {
    const int i = ibase + r;
    const int ridx = fr - i + MAX_REL;
    const int src = (lane & 48) | (ridx & 15);
    float g0 = __shfl(G0[r], src);
    float g1 = __shfl(G1[r], src);
    float g = (ridx >= 16) ? g1 : g0;
    float s = (accS[r] + g) * 0.125f;
    float mx = s;
#pragma unroll
    for (int w = 8; w >= 1; w >>= 1) mx = fmaxf(mx, __shfl_xor(mx, w));
    float e = __expf(s - mx);
    float sum = e;
#pragma unroll
    for (int w = 8; w >= 1; w >>= 1) sum += __shfl_xor(sum, w);
    _Float16 ph = (_Float16)(e / sum);
    PB[wave][i][fr] = ph;
    PB[wave][i][32 + (fr - i + MAX_REL)] = ph;
  }

  half8 aP0 = *(const half8*)&PB[wave][fr][fk8];
  half8 aP1 = *(const half8*)&PB[wave][fr][32 + fk8];
  const size_t obase = (size_t)(b * T_SEQ) * D_MODEL + h * 64;
#pragma unroll
  for (int t = 0; t < 4; ++t) {
    half8 bv = *(const half8*)&VtP[wave][t * 16 + fr][fk8];
    half8 br = *(const half8*)&RVt[t * 16 + fr][fk8];
    f32x4 o = {0.f, 0.f, 0.f, 0.f};
    o = __builtin_amdgcn_mfma_f32_16x16x32_f16(aP0, bv, o, 0, 0, 0);
    o = __builtin_amdgcn_mfma_f32_16x16x32_f16(aP1, br, o, 0, 0, 0);
#pragma unroll
    for (int r = 0; r < 4; ++r)
      O[obase + (size_t)(ibase + r) * D_MODEL + t * 16 + fr] = (_Float16)o[r];
  }
}

// ---------------------------------------------------------------------------
extern "C" void kernel_launch(void* const* d_in, const int* in_sizes, int n_in,
                              void* d_out, int out_size, void* d_ws, size_t ws_size,
                              hipStream_t stream) {
  const float* x  = (const float*)d_in[0];
  const float* Wq = (const float*)d_in[1];
  const float* Wk = (const float*)d_in[2];
  const float* Wv = (const float*)d_in[3];
  const float* Wo = (const float*)d_in[4];
  const float* bo = (const float*)d_in[5];
  const float* rk = (const float*)d_in[6];
  const float* rv = (const float*)d_in[7];
  float* out = (float*)d_out;

  const int total_rows = 2048 * T_SEQ;           // 32768
  const size_t wsz = (size_t)D_MODEL * D_MODEL;  // 1M elems per weight

  _Float16* Wqkvh = (_Float16*)d_ws;
  _Float16* Woh = Wqkvh + 3 * wsz;
  _Float16* chunk_base = Woh + wsz;

  {
    int n8 = (int)(wsz / 8);
    int blocks = (n8 + 255) / 256;
    cvt_f32_f16<<<blocks, 256, 0, stream>>>(Wq, Wqkvh, n8);
    cvt_f32_f16<<<blocks, 256, 0, stream>>>(Wk, Wqkvh + wsz, n8);
    cvt_f32_f16<<<blocks, 256, 0, stream>>>(Wv, Wqkvh + 2 * wsz, n8);
    cvt_f32_f16<<<blocks, 256, 0, stream>>>(Wo, Woh, n8);
  }

  // per-chunk: xh (1024) + QKV (3072) + AO (1024) fp16 per row
  const size_t per_row_bytes = (size_t)5120 * sizeof(_Float16);
  size_t avail = ws_size - (size_t)4 * wsz * sizeof(_Float16);
  size_t rows_fit = avail / per_row_bytes;
  int rows_c = (rows_fit > (size_t)total_rows) ? total_rows : (int)rows_fit;
  rows_c = (rows_c / 256) * 256;
  if (rows_c < 256) rows_c = 256;

  for (int r0 = 0; r0 < total_rows; r0 += rows_c) {
    int rc = total_rows - r0;
    if (rc > rows_c) rc = rows_c;

    _Float16* xh   = chunk_base;
    _Float16* QKVb = xh + (size_t)rows_c * 1024;
    _Float16* AO   = QKVb + (size_t)rows_c * 3072;

    {
      int n8 = rc * 128;
      cvt_f32_f16<<<(n8 + 255) / 256, 256, 0, stream>>>(
          x + (size_t)r0 * D_MODEL, xh, n8);
    }

    dim3 g1(3072 / 256, rc / 256);
    gemm256<true><<<g1, 512, 0, stream>>>(xh, Wqkvh, nullptr, QKVb,
                                          rc, 3072, 1024);

    attn_mfma<<<rc / 4, 256, 0, stream>>>(QKVb, rk, rv, AO);

    dim3 g2(1024 / 256, rc / 256);
    gemm256<false><<<g2, 512, 0, stream>>>(AO, Woh, bo, out + (size_t)r0 * D_MODEL,
                                           rc, 1024, 1024);
  }
}

// Round 5
// 414.633 us; speedup vs baseline: 8.2534x; 1.0065x over previous
//
#include <hip/hip_runtime.h>

#define HEADS 16
#define DIM_HEAD 64
#define T_SEQ 16
#define D_MODEL 1024
#define MAX_REL 16

typedef _Float16 half8 __attribute__((ext_vector_type(8)));
typedef float f32x4 __attribute__((ext_vector_type(4)));

// ---------------------------------------------------------------------------
// fp32 -> fp16 conversion, 8 elems/thread
// ---------------------------------------------------------------------------
__global__ __launch_bounds__(256)
void cvt_f32_f16(const float* __restrict__ in, _Float16* __restrict__ out, int n8) {
  int i = blockIdx.x * blockDim.x + threadIdx.x;
  if (i >= n8) return;
  float4 a = ((const float4*)in)[2 * i];
  float4 b = ((const float4*)in)[2 * i + 1];
  half8 h;
  h[0] = (_Float16)a.x; h[1] = (_Float16)a.y;
  h[2] = (_Float16)a.z; h[3] = (_Float16)a.w;
  h[4] = (_Float16)b.x; h[5] = (_Float16)b.y;
  h[6] = (_Float16)b.z; h[7] = (_Float16)b.w;
  ((half8*)out)[i] = h;
}

// ---------------------------------------------------------------------------
// async global -> LDS, 16B per lane (dest = wave-uniform base + lane*16)
// ---------------------------------------------------------------------------
__device__ __forceinline__ void gload_lds16(const _Float16* g, _Float16* l) {
  __builtin_amdgcn_global_load_lds(
      (const __attribute__((address_space(1))) unsigned int*)(uintptr_t)g,
      (__attribute__((address_space(3))) unsigned int*)(uintptr_t)l, 16, 0, 0);
}

// ---------------------------------------------------------------------------
// 256x256 MFMA fp16 GEMM, BK=64, 8 waves (2M x 4N), phase-split pipeline.
// C[M,N] = A[M,K]*B[N,K]^T. LDS [buf][A/B][half][128][64] fp16 = 128 KB,
// XOR-swizzled 16B slots (slot ^= row&7), staged via global_load_lds with
// pre-swizzled global source. Tile t+1 staged early (phases 0-1) so the
// p3 vmcnt(0) drain has 2+ phases of cover. XCD-chunked block remap.
// ---------------------------------------------------------------------------
template <bool OUT_F16>
__global__ __launch_bounds__(512, 2)
void gemm256(const _Float16* __restrict__ A, const _Float16* __restrict__ B,
             const float* __restrict__ bias, void* __restrict__ Cv,
             int M, int N, int K) {
  __shared__ _Float16 lds[2][2][2][128][64];
  const int tid = threadIdx.x;
  const int wave = tid >> 6, lane = tid & 63;
  const int wm = wave >> 2, wn = wave & 3;

  // ---- XCD-aware bijective remap (m204): each XCD owns a contiguous
  // bm-stripe of the (bm-major, bn-fast) index space.
  const int GN = N >> 8;
  const int nwg = gridDim.x;
  const int q = nwg >> 3, r = nwg & 7;
  {
  }
  const int xcd = blockIdx.x & 7, pos = blockIdx.x >> 3;
  const int wgid = (xcd < r ? xcd * (q + 1) : r * (q + 1) + (xcd - r) * q) + pos;
  const int bm = wgid / GN, bn = wgid % GN;

  const int fr = lane & 15;          // frag row/col within 16
  const int q4 = lane >> 4;          // 0..3 : 16B slot within 64B k-half
  const int l3 = lane >> 3;          // staging row within 8-row group
  const int sl = (lane & 7) ^ l3;    // pre-swizzled source slot

  const _Float16* Ag = A + (size_t)(bm * 256) * K;
  const _Float16* Bg = B + (size_t)(bn * 256) * K;

  f32x4 acc[8][4];
#pragma unroll
  for (int m = 0; m < 8; ++m)
#pragma unroll
    for (int n = 0; n < 4; ++n) acc[m][n] = (f32x4){0.f, 0.f, 0.f, 0.f};

  // stage one 128x64 half-tile (2 x gload_lds per thread)
  auto stage_half = [&](int buf, int ab, int half, const _Float16* G, int k0) {
#pragma unroll
    for (int i = 0; i < 2; ++i) {
      int g = wave * 2 + i;  // 8-row group 0..15
      const _Float16* src =
          G + (size_t)(half * 128 + g * 8 + l3) * K + k0 + sl * 8;
      gload_lds16(src, &lds[buf][ab][half][g * 8][0]);
    }
  };

  auto ldA = [&](int buf, int mf, int ks) {
    unsigned off = (unsigned)((mf * 16 + fr) * 128 + (ks * 4 + q4) * 16) ^
                   (unsigned)((fr & 7) << 4);
    return *(const half8*)((const char*)&lds[buf][0][wm][0][0] + off);
  };
  auto ldB = [&](int buf, int nf, int ks) {
    int rowB = wn * 64 + nf * 16 + fr;
    unsigned off = (unsigned)((rowB & 127) * 128 + (ks * 4 + q4) * 16) ^
                   (unsigned)((fr & 7) << 4);
    return *(const half8*)((const char*)&lds[buf][1][rowB >> 7][0][0] + off);
  };

  // prologue: stage tile 0 fully
#pragma unroll
  for (int h = 0; h < 2; ++h) {
    stage_half(0, 0, h, Ag, 0);
    stage_half(0, 1, h, Bg, 0);
  }
  asm volatile("s_waitcnt vmcnt(0)" ::: "memory");
  __builtin_amdgcn_s_barrier();

  const int NT = K >> 6;
  for (int t = 0; t < NT; ++t) {
    const int cur = t & 1, nxt = cur ^ 1;
    const bool pf = (t + 1 < NT);
    const int k1 = (t + 1) << 6;
    half8 bF[4][2];
#pragma unroll
    for (int p = 0; p < 4; ++p) {
      // ---- region A: ds_reads for this phase's quadrant + early staging
      half8 aF[2][2];
#pragma unroll
      for (int i = 0; i < 2; ++i)
#pragma unroll
        for (int ks = 0; ks < 2; ++ks) aF[i][ks] = ldA(cur, p * 2 + i, ks);
      if (p == 0) {
#pragma unroll
        for (int nf = 0; nf < 4; ++nf)
#pragma unroll
          for (int ks = 0; ks < 2; ++ks) bF[nf][ks] = ldB(cur, nf, ks);
      }
      if (pf) {
        if (p == 0) {          // stage both A-halves of tile t+1
          stage_half(nxt, 0, 0, Ag, k1);
          stage_half(nxt, 0, 1, Ag, k1);
        } else if (p == 1) {   // stage both B-halves of tile t+1
          stage_half(nxt, 1, 0, Bg, k1);
          stage_half(nxt, 1, 1, Bg, k1);
        }
      }
      __builtin_amdgcn_s_barrier();
      asm volatile("s_waitcnt lgkmcnt(0)" ::: "memory");
      __builtin_amdgcn_sched_barrier(0);
      // ---- region B: 16 MFMA (quadrant p x K=64)
      __builtin_amdgcn_s_setprio(1);
#pragma unroll
      for (int i = 0; i < 2; ++i)
#pragma unroll
        for (int nf = 0; nf < 4; ++nf)
#pragma unroll
          for (int ks = 0; ks < 2; ++ks)
            acc[p * 2 + i][nf] = __builtin_amdgcn_mfma_f32_16x16x32_f16(
                aF[i][ks], bF[nf][ks], acc[p * 2 + i][nf], 0, 0, 0);
      __builtin_amdgcn_s_setprio(0);
      __builtin_amdgcn_sched_barrier(0);
      if (p == 3) asm volatile("s_waitcnt vmcnt(0)" ::: "memory");
      __builtin_amdgcn_s_barrier();
    }
  }

  // ---- epilogue ----
  const int row_l = q4 * 4;
#pragma unroll
  for (int mf = 0; mf < 8; ++mf) {
#pragma unroll
    for (int nf = 0; nf < 4; ++nf) {
      int col = bn * 256 + wn * 64 + nf * 16 + fr;
#pragma unroll
      for (int r4 = 0; r4 < 4; ++r4) {
        int row = bm * 256 + wm * 128 + mf * 16 + row_l + r4;
        if (OUT_F16) {
          ((_Float16*)Cv)[(size_t)row * N + col] = (_Float16)acc[mf][nf][r4];
        } else {
          ((float*)Cv)[(size_t)row * N + col] = acc[mf][nf][r4] + bias[col];
        }
      }
    }
  }
}

// ---------------------------------------------------------------------------
// MFMA attention: one wave per head, 4 heads per block. (unchanged, passing)
// ---------------------------------------------------------------------------
__global__ __launch_bounds__(256)
void attn_mfma(const _Float16* __restrict__ QKV,
               const float* __restrict__ relk, const float* __restrict__ relv,
               _Float16* __restrict__ O) {
  __shared__ _Float16 RK[32][72];
  __shared__ _Float16 RVt[64][40];
  __shared__ _Float16 PB[4][16][72];
  __shared__ _Float16 VtP[4][64][40];

  const int tid = threadIdx.x;
  const int wave = tid >> 6, lane = tid & 63;

  {
    int m = tid >> 3;
    int d0 = (tid & 7) * 8;
    float4 a = *(const float4*)(relk + m * 64 + d0);
    float4 b = *(const float4*)(relk + m * 64 + d0 + 4);
    half8 hk;
    hk[0] = (_Float16)a.x; hk[1] = (_Float16)a.y;
    hk[2] = (_Float16)a.z; hk[3] = (_Float16)a.w;
    hk[4] = (_Float16)b.x; hk[5] = (_Float16)b.y;
    hk[6] = (_Float16)b.z; hk[7] = (_Float16)b.w;
    *(half8*)&RK[m][d0] = hk;
    float4 c = *(const float4*)(relv + m * 64 + d0);
    float4 d = *(const float4*)(relv + m * 64 + d0 + 4);
    RVt[d0 + 0][m] = (_Float16)c.x; RVt[d0 + 1][m] = (_Float16)c.y;
    RVt[d0 + 2][m] = (_Float16)c.z; RVt[d0 + 3][m] = (_Float16)c.w;
    RVt[d0 + 4][m] = (_Float16)d.x; RVt[d0 + 5][m] = (_Float16)d.y;
    RVt[d0 + 6][m] = (_Float16)d.z; RVt[d0 + 7][m] = (_Float16)d.w;
  }

#pragma unroll
  for (int z = 0; z < 6; ++z) {
    int idx = z * 64 + lane;
    int row = idx / 24, cd = idx % 24;
    *(unsigned int*)&PB[wave][row][16 + 2 * cd] = 0u;
  }
#pragma unroll
  for (int z = 0; z < 8; ++z) {
    int idx = z * 64 + lane;
    int row = idx >> 3, cd = idx & 7;
    *(unsigned int*)&VtP[wave][row][16 + 2 * cd] = 0u;
  }

  const int bh = blockIdx.x * 4 + wave;
  const int b = bh >> 4, h = bh & 15;
  const size_t qbase = (size_t)(b * T_SEQ) * 3072 + h * 64;
  const int fr = lane & 15, fk8 = (lane >> 4) * 8;

  half8 aQ0 = *(const half8*)(QKV + qbase + (size_t)fr * 3072 + fk8);
  half8 aQ1 = *(const half8*)(QKV + qbase + (size_t)fr * 3072 + 32 + fk8);
  half8 bK0 = *(const half8*)(QKV + qbase + 1024 + (size_t)fr * 3072 + fk8);
  half8 bK1 = *(const half8*)(QKV + qbase + 1024 + (size_t)fr * 3072 + 32 + fk8);

  {
    const _Float16* vp = QKV + qbase + 2048 + (size_t)fr * 3072 + (lane >> 4) * 16;
    half8 v0 = *(const half8*)vp;
    half8 v1 = *(const half8*)(vp + 8);
    int d0 = (lane >> 4) * 16;
#pragma unroll
    for (int e = 0; e < 8; ++e) VtP[wave][d0 + e][fr] = v0[e];
#pragma unroll
    for (int e = 0; e < 8; ++e) VtP[wave][d0 + 8 + e][fr] = v1[e];
  }

  __syncthreads();

  f32x4 accS = {0.f, 0.f, 0.f, 0.f};
  accS = __builtin_amdgcn_mfma_f32_16x16x32_f16(aQ0, bK0, accS, 0, 0, 0);
  accS = __builtin_amdgcn_mfma_f32_16x16x32_f16(aQ1, bK1, accS, 0, 0, 0);

  half8 rk0a = *(const half8*)&RK[fr][fk8];
  half8 rk0b = *(const half8*)&RK[fr][32 + fk8];
  half8 rk1a = *(const half8*)&RK[16 + fr][fk8];
  half8 rk1b = *(const half8*)&RK[16 + fr][32 + fk8];
  f32x4 G0 = {0.f, 0.f, 0.f, 0.f}, G1 = {0.f, 0.f, 0.f, 0.f};
  G0 = __builtin_amdgcn_mfma_f32_16x16x32_f16(aQ0, rk0a, G0, 0, 0, 0);
  G0 = __builtin_amdgcn_mfma_f32_16x16x32_f16(aQ1, rk0b, G0, 0, 0, 0);
  G1 = __builtin_amdgcn_mfma_f32_16x16x32_f16(aQ0, rk1a, G1, 0, 0, 0);
  G1 = __builtin_amdgcn_mfma_f32_16x16x32_f16(aQ1, rk1b, G1, 0, 0, 0);

  const int ibase = (lane >> 4) * 4;
#pragma unroll
  for (int r = 0; r < 4; ++r) {
    const int i = ibase + r;
    const int ridx = fr - i + MAX_REL;
    const int src = (lane & 48) | (ridx & 15);
    float g0 = __shfl(G0[r], src);
    float g1 = __shfl(G1[r], src);
    float g = (ridx >= 16) ? g1 : g0;
    float s = (accS[r] + g) * 0.125f;
    float mx = s;
#pragma unroll
    for (int w = 8; w >= 1; w >>= 1) mx = fmaxf(mx, __shfl_xor(mx, w));
    float e = __expf(s - mx);
    float sum = e;
#pragma unroll
    for (int w = 8; w >= 1; w >>= 1) sum += __shfl_xor(sum, w);
    _Float16 ph = (_Float16)(e / sum);
    PB[wave][i][fr] = ph;
    PB[wave][i][32 + (fr - i + MAX_REL)] = ph;
  }

  half8 aP0 = *(const half8*)&PB[wave][fr][fk8];
  half8 aP1 = *(const half8*)&PB[wave][fr][32 + fk8];
  const size_t obase = (size_t)(b * T_SEQ) * D_MODEL + h * 64;
#pragma unroll
  for (int t = 0; t < 4; ++t) {
    half8 bv = *(const half8*)&VtP[wave][t * 16 + fr][fk8];
    half8 br = *(const half8*)&RVt[t * 16 + fr][fk8];
    f32x4 o = {0.f, 0.f, 0.f, 0.f};
    o = __builtin_amdgcn_mfma_f32_16x16x32_f16(aP0, bv, o, 0, 0, 0);
    o = __builtin_amdgcn_mfma_f32_16x16x32_f16(aP1, br, o, 0, 0, 0);
#pragma unroll
    for (int r = 0; r < 4; ++r)
      O[obase + (size_t)(ibase + r) * D_MODEL + t * 16 + fr] = (_Float16)o[r];
  }
}

// ---------------------------------------------------------------------------
extern "C" void kernel_launch(void* const* d_in, const int* in_sizes, int n_in,
                              void* d_out, int out_size, void* d_ws, size_t ws_size,
                              hipStream_t stream) {
  const float* x  = (const float*)d_in[0];
  const float* Wq = (const float*)d_in[1];
  const float* Wk = (const float*)d_in[2];
  const float* Wv = (const float*)d_in[3];
  const float* Wo = (const float*)d_in[4];
  const float* bo = (const float*)d_in[5];
  const float* rk = (const float*)d_in[6];
  const float* rv = (const float*)d_in[7];
  float* out = (float*)d_out;

  const int total_rows = 2048 * T_SEQ;           // 32768
  const size_t wsz = (size_t)D_MODEL * D_MODEL;  // 1M elems per weight

  _Float16* Wqkvh = (_Float16*)d_ws;
  _Float16* Woh = Wqkvh + 3 * wsz;
  _Float16* chunk_base = Woh + wsz;

  {
    int n8 = (int)(wsz / 8);
    int blocks = (n8 + 255) / 256;
    cvt_f32_f16<<<blocks, 256, 0, stream>>>(Wq, Wqkvh, n8);
    cvt_f32_f16<<<blocks, 256, 0, stream>>>(Wk, Wqkvh + wsz, n8);
    cvt_f32_f16<<<blocks, 256, 0, stream>>>(Wv, Wqkvh + 2 * wsz, n8);
    cvt_f32_f16<<<blocks, 256, 0, stream>>>(Wo, Woh, n8);
  }

  // per-chunk: xh (1024) + QKV (3072) + AO (1024) fp16 per row
  const size_t per_row_bytes = (size_t)5120 * sizeof(_Float16);
  size_t avail = ws_size - (size_t)4 * wsz * sizeof(_Float16);
  size_t rows_fit = avail / per_row_bytes;
  int rows_c = (rows_fit > (size_t)total_rows) ? total_rows : (int)rows_fit;
  rows_c = (rows_c / 256) * 256;
  if (rows_c < 256) rows_c = 256;

  for (int r0 = 0; r0 < total_rows; r0 += rows_c) {
    int rc = total_rows - r0;
    if (rc > rows_c) rc = rows_c;

    _Float16* xh   = chunk_base;
    _Float16* QKVb = xh + (size_t)rows_c * 1024;
    _Float16* AO   = QKVb + (size_t)rows_c * 3072;

    {
      int n8 = rc * 128;
      cvt_f32_f16<<<(n8 + 255) / 256, 256, 0, stream>>>(
          x + (size_t)r0 * D_MODEL, xh, n8);
    }

    gemm256<true><<<(3072 / 256) * (rc / 256), 512, 0, stream>>>(
        xh, Wqkvh, nullptr, QKVb, rc, 3072, 1024);

    attn_mfma<<<rc / 4, 256, 0, stream>>>(QKVb, rk, rv, AO);

    gemm256<false><<<(1024 / 256) * (rc / 256), 512, 0, stream>>>(
        AO, Woh, bo, out + (size_t)r0 * D_MODEL, rc, 1024, 1024);
  }
}